// Round 1
// baseline (1454.763 us; speedup 1.0000x reference)
//
#include <hip/hip_runtime.h>
#include <cstdint>
#include <cstddef>

// Attention with tanh_max normalizer, B=4 H=12 S=2048 D=32, fp32 in/out.
//   num[q,d] = sum_k (e^{s_qk} - e^{-s_qk}) * V[k,d]
//   den[q]   = sum_k (e^{s_qk} + e^{-s_qk})
//   out      = num / den        (attn_mask is a faithful no-op -> never read)
// No max-subtraction needed: |s| <~ 7 for N(0,1)-ish scores.
//
// Layout: grid = 48 heads * 32 q-tiles = 1536 blocks, 256 thr = 4 waves.
// Lane owns one query row (q + acc in VGPRs); the 4 waves split the 2048
// keys 4-way (512 each); partial num/den combined through LDS at the end.
// K/V staged per-wave in 32-key chunks via global_load_lds width=16.

#define S_LEN 2048
#define D_K   32
#define QT    64    // queries per block (one per lane)
#define KPW   512   // keys per wave
#define KCH   32    // keys per staged chunk

typedef const __attribute__((address_space(1))) void* gas_ptr;
typedef __attribute__((address_space(3))) void*       las_ptr;

__global__ __launch_bounds__(256, 3)
void attn_tanhmax(const float* __restrict__ Q,
                  const float* __restrict__ K,
                  const float* __restrict__ V,
                  float* __restrict__ Out)
{
    // staging: 4 waves * (1024 K floats + 1024 V floats) = 8192 floats
    // reduction reuses each wave's own staging region + 256 floats for den
    __shared__ float smem[4 * 2048 + 4 * 64];   // 33,792 B

    const int tid  = threadIdx.x;
    const int lane = tid & 63;
    const int wv   = tid >> 6;
    const int bh   = blockIdx.x >> 5;   // 0..47  (b*H + h)
    const int qt   = blockIdx.x & 31;   // 0..31

    const float* Qp = Q + ((size_t)(bh * S_LEN + qt * QT + lane)) * D_K;
    const float* Kh = K + (size_t)bh * S_LEN * D_K;
    const float* Vh = V + (size_t)bh * S_LEN * D_K;

    // q row, pre-scaled by 1/sqrt(32)
    float q[D_K];
    {
        const float4* q4 = (const float4*)Qp;
        #pragma unroll
        for (int i = 0; i < 8; ++i) {
            float4 t = q4[i];
            q[4*i+0] = t.x * 0.17677669529663687f;
            q[4*i+1] = t.y * 0.17677669529663687f;
            q[4*i+2] = t.z * 0.17677669529663687f;
            q[4*i+3] = t.w * 0.17677669529663687f;
        }
    }

    float acc[D_K];
    #pragma unroll
    for (int i = 0; i < D_K; ++i) acc[i] = 0.0f;
    float den = 0.0f;

    float* ldsK = smem + wv * 2048;      // 1024 floats (32 keys x 32 d)
    float* ldsV = ldsK + 1024;

    const int kbase0 = wv * KPW;

    for (int c = 0; c < KPW / KCH; ++c) {
        const float* gK = Kh + (size_t)(kbase0 + c * KCH) * D_K;
        const float* gV = Vh + (size_t)(kbase0 + c * KCH) * D_K;
        // stage 32x32 K tile + 32x32 V tile: 8x global_load_lds dwordx4
        // (lane i's 16B lands at ldsbase + i*16 -- contiguous row-major copy)
        #pragma unroll
        for (int i = 0; i < 4; ++i) {
            __builtin_amdgcn_global_load_lds(
                (gas_ptr)(gK + i * 256 + lane * 4),
                (las_ptr)(ldsK + i * 256), 16, 0, 0);
            __builtin_amdgcn_global_load_lds(
                (gas_ptr)(gV + i * 256 + lane * 4),
                (las_ptr)(ldsV + i * 256), 16, 0, 0);
        }
        __builtin_amdgcn_s_waitcnt(0x0f70);   // vmcnt(0), lgkm/exp unmasked

        #pragma unroll 2
        for (int k = 0; k < KCH; ++k) {
            const float4* kr = (const float4*)(ldsK + k * 32);
            const float4* vr = (const float4*)(ldsV + k * 32);
            // dot(q, k_row): 4 independent partial chains
            float s0 = 0.f, s1 = 0.f, s2 = 0.f, s3 = 0.f;
            #pragma unroll
            for (int i = 0; i < 2; ++i) {
                float4 a = kr[4*i+0], b = kr[4*i+1], cc = kr[4*i+2], d4 = kr[4*i+3];
                s0 += q[16*i+ 0]*a.x  + q[16*i+ 1]*a.y  + q[16*i+ 2]*a.z  + q[16*i+ 3]*a.w;
                s1 += q[16*i+ 4]*b.x  + q[16*i+ 5]*b.y  + q[16*i+ 6]*b.z  + q[16*i+ 7]*b.w;
                s2 += q[16*i+ 8]*cc.x + q[16*i+ 9]*cc.y + q[16*i+10]*cc.z + q[16*i+11]*cc.w;
                s3 += q[16*i+12]*d4.x + q[16*i+13]*d4.y + q[16*i+14]*d4.z + q[16*i+15]*d4.w;
            }
            float s  = (s0 + s1) + (s2 + s3);
            float e  = __expf(s);
            float en = __expf(-s);
            float w  = e - en;
            den     += e + en;
            #pragma unroll
            for (int i = 0; i < 8; ++i) {
                float4 t = vr[i];
                acc[4*i+0] += w * t.x;
                acc[4*i+1] += w * t.y;
                acc[4*i+2] += w * t.z;
                acc[4*i+3] += w * t.w;
            }
        }
    }

    // ---- cross-wave combine: each wave writes into ITS OWN staging region
    // (no hazard with other waves still reading theirs), then barrier.
    // layout: smem[wv*2048 + d*64 + lane]  (bank = lane%32 -> 2-way, free)
    #pragma unroll
    for (int d = 0; d < D_K; ++d)
        smem[wv * 2048 + d * 64 + lane] = acc[d];
    smem[4 * 2048 + wv * 64 + lane] = den;
    __syncthreads();

    // 256 threads -> thread t handles query l = t/4, dims [dg*8, dg*8+8)
    const int l  = tid >> 2;
    const int dg = tid & 3;
    float dsum = smem[4*2048 +   0 + l] + smem[4*2048 +  64 + l]
               + smem[4*2048 + 128 + l] + smem[4*2048 + 192 + l];
    float inv = 1.0f / dsum;

    float o[8];
    #pragma unroll
    for (int j = 0; j < 8; ++j) {
        int di = dg * 8 + j;
        float n = smem[0*2048 + di*64 + l] + smem[1*2048 + di*64 + l]
                + smem[2*2048 + di*64 + l] + smem[3*2048 + di*64 + l];
        o[j] = n * inv;
    }
    float* orow = Out + ((size_t)(bh * S_LEN + qt * QT + l)) * D_K + dg * 8;
    float4* o4 = (float4*)orow;
    o4[0] = make_float4(o[0], o[1], o[2], o[3]);
    o4[1] = make_float4(o[4], o[5], o[6], o[7]);
}

extern "C" void kernel_launch(void* const* d_in, const int* in_sizes, int n_in,
                              void* d_out, int out_size, void* d_ws, size_t ws_size,
                              hipStream_t stream) {
    const float* Q = (const float*)d_in[0];
    const float* K = (const float*)d_in[1];
    const float* V = (const float*)d_in[2];
    // d_in[3] = attn_mask: faithful no-op in the reference -> never read
    float* Out = (float*)d_out;
    dim3 grid(48 * 32);   // BH * (S/QT)
    dim3 block(256);
    attn_tanhmax<<<grid, block, 0, stream>>>(Q, K, V, Out);
}

// Round 2
// 1128.910 us; speedup vs baseline: 1.2886x; 1.2886x over previous
//
#include <hip/hip_runtime.h>
#include <hip/hip_bf16.h>
#include <cstdint>
#include <cstddef>

// tanh_max attention, B=4 H=12 S=2048 D=32, fp32 in/out. attn_mask is a
// faithful no-op in the reference -> never read.
//
// R2: bf16 MFMA rewrite.
//   - D=32 == K-dim of mfma_f32_16x16x32_bf16: one MFMA per 16q x 16k score
//     tile; A(Q) and B(K^T) frags are contiguous 16B-per-lane global loads.
//   - Prep kernel materializes V^T bf16 [48][32][2048] in d_ws so the PV
//     B-frag is also a contiguous 16B global load.
//   - P = (e^s - e^-s) converts C-layout -> A-layout via a per-wave LDS
//     round trip (8 ds_write_b16 + 1 ds_read_b128 per 32-key chunk).
//   - den = sum(e^s + e^-s) stays fp32 in VGPRs; shfl_xor(16) reduction.
//   - No __syncthreads in the main kernel; each wave owns 16 queries.

#define SLEN 2048
#define DK   32
#define NBH  48
#define PROW 40   // P-buffer row stride in bf16 elems (80 B, 16B-aligned)

typedef __attribute__((ext_vector_type(8))) short bf16x8;
typedef __attribute__((ext_vector_type(4))) float f32x4;

__device__ __forceinline__ unsigned pk2(float a, float b) {
    __hip_bfloat162 h = __float22bfloat162_rn(make_float2(a, b));
    union { __hip_bfloat162 h2; unsigned u; } cv; cv.h2 = h; return cv.u;
}
__device__ __forceinline__ unsigned short f2b(float x) {
    __hip_bfloat16 h = __float2bfloat16(x);
    union { __hip_bfloat16 h; unsigned short u; } cv; cv.h = h; return cv.u;
}

// ---- pass 1: V [bh][k][d] fp32 -> VT [bh][d][k] bf16 ------------------------
__global__ __launch_bounds__(256)
void prep_vt(const float* __restrict__ V, unsigned short* __restrict__ VT) {
    __shared__ float tile[32][33];
    const int bh = blockIdx.x >> 6;   // 48 heads
    const int kc = blockIdx.x & 63;   // 64 chunks of 32 keys
    const int t  = threadIdx.x;
    const int row = t >> 3, c4 = (t & 7) * 4;
    float4 v4 = *(const float4*)(V + ((size_t)bh * SLEN + kc * 32 + row) * DK + c4);
    tile[row][c4 + 0] = v4.x; tile[row][c4 + 1] = v4.y;
    tile[row][c4 + 2] = v4.z; tile[row][c4 + 3] = v4.w;
    __syncthreads();
    const int d = t >> 3, k4 = (t & 7) * 4;
    float a0 = tile[k4 + 0][d], a1 = tile[k4 + 1][d];
    float a2 = tile[k4 + 2][d], a3 = tile[k4 + 3][d];
    uint2 u; u.x = pk2(a0, a1); u.y = pk2(a2, a3);
    *(uint2*)(VT + ((size_t)bh * DK + d) * SLEN + kc * 32 + k4) = u;
}

// ---- pass 2: flash-style MFMA attention ------------------------------------
__global__ __launch_bounds__(256, 4)
void attn_mfma(const float* __restrict__ Q, const float* __restrict__ K,
               const unsigned short* __restrict__ VT, float* __restrict__ Out) {
    __shared__ __align__(16) unsigned short Pbuf[4][16 * PROW];  // 5120 B

    const int tid  = threadIdx.x;
    const int lane = tid & 63;
    const int wv   = tid >> 6;
    const int quad = lane >> 4;
    const int l16  = lane & 15;

    const int g     = blockIdx.x * 4 + wv;   // global 16-query tile id
    const int bh    = g >> 7;                // 128 tiles per head
    const int qbase = (g & 127) << 4;

    // Q a-frag: lane holds Q[q = qbase+l16][quad*8 .. +7], scaled by
    // (1/sqrt(32)) * log2(e) so MFMA emits log2-domain scores directly.
    const float sc = 0.17677669529663687f * 1.4426950408889634f;
    const float* qp = Q + ((size_t)bh * SLEN + qbase + l16) * DK + quad * 8;
    float4 qa = *(const float4*)qp;
    float4 qb = *(const float4*)(qp + 4);
    union { bf16x8 v; unsigned u[4]; } aQ;
    aQ.u[0] = pk2(qa.x * sc, qa.y * sc); aQ.u[1] = pk2(qa.z * sc, qa.w * sc);
    aQ.u[2] = pk2(qb.x * sc, qb.y * sc); aQ.u[3] = pk2(qb.z * sc, qb.w * sc);

    f32x4 o0 = {0.f, 0.f, 0.f, 0.f};   // out[q][d 0..15]
    f32x4 o1 = {0.f, 0.f, 0.f, 0.f};   // out[q][d 16..31]
    const f32x4 zero = {0.f, 0.f, 0.f, 0.f};
    float den[4] = {0.f, 0.f, 0.f, 0.f};

    const float* kp = K + ((size_t)bh * SLEN + l16) * DK + quad * 8;
    const unsigned short* vp = VT + ((size_t)bh * DK + l16) * SLEN;
    unsigned short* pb = &Pbuf[wv][0];

    #pragma unroll 2
    for (int kb = 0; kb < SLEN; kb += 32) {
        // K b-frags (keys kb..kb+15 and kb+16..kb+31), fp32 -> bf16 on the fly
        const float* k0 = kp + (size_t)kb * DK;
        float4 ka = *(const float4*)k0,            kb4 = *(const float4*)(k0 + 4);
        float4 kc = *(const float4*)(k0 + 16*DK),  kd  = *(const float4*)(k0 + 16*DK + 4);
        union { bf16x8 v; unsigned u[4]; } bK0, bK1;
        bK0.u[0] = pk2(ka.x, ka.y);  bK0.u[1] = pk2(ka.z, ka.w);
        bK0.u[2] = pk2(kb4.x, kb4.y); bK0.u[3] = pk2(kb4.z, kb4.w);
        bK1.u[0] = pk2(kc.x, kc.y);  bK1.u[1] = pk2(kc.z, kc.w);
        bK1.u[2] = pk2(kd.x, kd.y);  bK1.u[3] = pk2(kd.z, kd.w);

        f32x4 s0 = __builtin_amdgcn_mfma_f32_16x16x32_bf16(aQ.v, bK0.v, zero, 0, 0, 0);
        f32x4 s1 = __builtin_amdgcn_mfma_f32_16x16x32_bf16(aQ.v, bK1.v, zero, 0, 0, 0);

        // scores (log2 domain): w = 2^t - 2^-t, den += 2^t + 2^-t
        // C-layout: lane holds S[q = quad*4+r][key col = l16 (+16 for s1)]
        #pragma unroll
        for (int r = 0; r < 4; ++r) {
            float e0  = exp2f(s0[r]);
            float en0 = exp2f(-s0[r]);
            den[r] += e0 + en0;
            pb[(quad * 4 + r) * PROW + l16] = f2b(e0 - en0);
            float e1  = exp2f(s1[r]);
            float en1 = exp2f(-s1[r]);
            den[r] += e1 + en1;
            pb[(quad * 4 + r) * PROW + 16 + l16] = f2b(e1 - en1);
        }

        // P: C-layout -> A-layout (lane holds P[q=l16][k = quad*8..+7])
        bf16x8 aP = *(const bf16x8*)(pb + l16 * PROW + quad * 8);

        // V b-frags from VT (contiguous 16B per lane)
        bf16x8 bV0 = *(const bf16x8*)(vp + kb + quad * 8);
        bf16x8 bV1 = *(const bf16x8*)(vp + 16 * SLEN + kb + quad * 8);

        o0 = __builtin_amdgcn_mfma_f32_16x16x32_bf16(aP, bV0, o0, 0, 0, 0);
        o1 = __builtin_amdgcn_mfma_f32_16x16x32_bf16(aP, bV1, o1, 0, 0, 0);
    }

    // den: sum across the 16 key-column lanes of each quad group
    #pragma unroll
    for (int r = 0; r < 4; ++r) {
        den[r] += __shfl_xor(den[r], 1, 16);
        den[r] += __shfl_xor(den[r], 2, 16);
        den[r] += __shfl_xor(den[r], 4, 16);
        den[r] += __shfl_xor(den[r], 8, 16);
    }

    float* outp = Out + ((size_t)bh * SLEN + qbase) * DK;
    #pragma unroll
    for (int r = 0; r < 4; ++r) {
        float inv = 1.0f / den[r];
        int q = quad * 4 + r;
        outp[(size_t)q * DK + l16]      = o0[r] * inv;
        outp[(size_t)q * DK + 16 + l16] = o1[r] * inv;
    }
}

extern "C" void kernel_launch(void* const* d_in, const int* in_sizes, int n_in,
                              void* d_out, int out_size, void* d_ws, size_t ws_size,
                              hipStream_t stream) {
    const float* Q = (const float*)d_in[0];
    const float* K = (const float*)d_in[1];
    const float* V = (const float*)d_in[2];
    // d_in[3] = attn_mask: no-op in reference, never read
    float* Out = (float*)d_out;
    unsigned short* VT = (unsigned short*)d_ws;   // 48*32*2048 bf16 = 6.3 MB

    prep_vt<<<dim3(NBH * 64), dim3(256), 0, stream>>>(V, VT);
    attn_mfma<<<dim3(NBH * 32), dim3(256), 0, stream>>>(Q, K, VT, Out);
}

// Round 3
// 934.274 us; speedup vs baseline: 1.5571x; 1.2083x over previous
//
#include <hip/hip_runtime.h>
#include <hip/hip_bf16.h>
#include <cstdint>
#include <cstddef>

// tanh_max attention, B=4 H=12 S=2048 D=32, fp32 in/out. attn_mask is a
// faithful no-op in the reference -> never read.
//
// R3: fragment-order pre-swizzle.
//   - prep_k: K fp32 -> Kbf bf16 in MFMA B-frag order, keys even/odd
//     interleaved per 32-key chunk (tile0 = even keys, tile1 = odd keys).
//   - prep_v: V fp32 -> VTf bf16 (V^T) in MFMA B-frag order, natural key
//     order.
//   - main loop loads are all `base + lane*16B` -> perfectly coalesced;
//     no fp32->bf16 cvt in the loop.
//   - even/odd interleave makes each lane's two P values adjacent ->
//     4x ds_write_b32 (packed) instead of 8x ds_write_b16.
//   - XCD swizzle: 6 heads per XCD -> 1.5 MB working set, L2-resident.
//   - explicit register prefetch of next chunk's 4 frags.

#define SLEN 2048
#define DK   32
#define NBH  48
#define PROW 40   // P-buffer row stride in bf16 (80 B, 16B-aligned)

typedef __attribute__((ext_vector_type(8))) short bf16x8;
typedef __attribute__((ext_vector_type(4))) float f32x4;

__device__ __forceinline__ unsigned pk2(float a, float b) {
    __hip_bfloat162 h = __float22bfloat162_rn(make_float2(a, b));
    union { __hip_bfloat162 h2; unsigned u; } cv; cv.h2 = h; return cv.u;
}

// ---- prep 1: K [bh][k][d] fp32 -> Kbf bf16 fragment-order -------------------
// Kbf elem ((bh*128 + t)*64 + l)*8 + j = K[bh][key(t,l)][(l>>4)*8 + j]
// where t = 2c+tb covers chunk c: key = c*32 + 2*(l&15) + tb.
__global__ __launch_bounds__(256)
void prep_k(const float* __restrict__ K, unsigned short* __restrict__ Kbf) {
    const int b  = blockIdx.x;
    const int bh = b >> 5, kg = b & 31;          // 64-key group
    const int tl = threadIdx.x >> 6, l = threadIdx.x & 63;
    const int t  = kg * 4 + tl;                  // global 16-key tile
    const int c  = t >> 1, tb = t & 1;
    const int key = c * 32 + 2 * (l & 15) + tb;
    const float* src = K + ((size_t)bh * SLEN + key) * DK + (l >> 4) * 8;
    float4 a = *(const float4*)src;
    float4 b4 = *(const float4*)(src + 4);
    union { uint4 q; unsigned u[4]; } o;
    o.u[0] = pk2(a.x, a.y);  o.u[1] = pk2(a.z, a.w);
    o.u[2] = pk2(b4.x, b4.y); o.u[3] = pk2(b4.z, b4.w);
    *(uint4*)(Kbf + (((size_t)bh * 128 + t) * 64 + l) * 8) = o.q;
}

// ---- prep 2: V [bh][k][d] fp32 -> VTf bf16 (V^T) fragment-order -------------
// VTf elem (((bh*64 + c)*2 + h)*64 + l)*8 + j = V[bh][c*32+(l>>4)*8+j][h*16+(l&15)]
__global__ __launch_bounds__(256)
void prep_v(const float* __restrict__ V, unsigned short* __restrict__ VTf) {
    __shared__ float tile[32][33];
    const int b  = blockIdx.x;
    const int bh = b >> 6, c = b & 63;
    const int t  = threadIdx.x;
    {
        const int row = t >> 3, c4 = (t & 7) * 4;
        float4 v4 = *(const float4*)(V + ((size_t)bh * SLEN + c * 32 + row) * DK + c4);
        tile[row][c4 + 0] = v4.x; tile[row][c4 + 1] = v4.y;
        tile[row][c4 + 2] = v4.z; tile[row][c4 + 3] = v4.w;
    }
    __syncthreads();
    const int h = t >> 7, l = (t >> 1) & 63, jh = t & 1;
    const int col = h * 16 + (l & 15);
    const int r0  = (l >> 4) * 8 + jh * 4;
    uint2 u;
    u.x = pk2(tile[r0 + 0][col], tile[r0 + 1][col]);
    u.y = pk2(tile[r0 + 2][col], tile[r0 + 3][col]);
    *(uint2*)(VTf + ((((size_t)bh * 64 + c) * 2 + h) * 64 + l) * 8 + jh * 4) = u;
}

// ---- main: flash-style MFMA attention, no barriers ---------------------------
__global__ __launch_bounds__(256, 4)
void attn_mfma(const float* __restrict__ Q, const unsigned short* __restrict__ Kbf,
               const unsigned short* __restrict__ VTf, float* __restrict__ Out) {
    __shared__ __align__(16) unsigned short Pbuf[4][16 * PROW];  // 5120 B

    const int tid  = threadIdx.x;
    const int lane = tid & 63;
    const int wv   = tid >> 6;
    const int quad = lane >> 4;
    const int l16  = lane & 15;

    // XCD-aware head clustering: blocks with blockIdx%8==x land on XCD x.
    const int b   = blockIdx.x;
    const int xcd = b & 7;
    const int i   = b >> 3;            // 0..191
    const int bh  = xcd * 6 + (i % 6); // 6 heads per XCD
    const int qt  = i / 6;             // 0..31
    const int qbase = (qt * 4 + wv) * 16;

    // Q a-frag, scaled by (1/sqrt(32))*log2(e) -> MFMA emits log2-domain scores
    const float sc = 0.17677669529663687f * 1.4426950408889634f;
    const float* qp = Q + ((size_t)bh * SLEN + qbase + l16) * DK + quad * 8;
    float4 qa = *(const float4*)qp;
    float4 qb = *(const float4*)(qp + 4);
    union { bf16x8 v; unsigned u[4]; } aQ;
    aQ.u[0] = pk2(qa.x * sc, qa.y * sc); aQ.u[1] = pk2(qa.z * sc, qa.w * sc);
    aQ.u[2] = pk2(qb.x * sc, qb.y * sc); aQ.u[3] = pk2(qb.z * sc, qb.w * sc);

    const bf16x8* kf = (const bf16x8*)Kbf + (size_t)bh * 128 * 64 + lane;
    const bf16x8* vf = (const bf16x8*)VTf + (size_t)bh * 128 * 64 + lane;

    f32x4 o0 = {0.f, 0.f, 0.f, 0.f};
    f32x4 o1 = {0.f, 0.f, 0.f, 0.f};
    const f32x4 zero = {0.f, 0.f, 0.f, 0.f};
    float den[4] = {0.f, 0.f, 0.f, 0.f};

    unsigned short* pb  = &Pbuf[wv][0];
    unsigned*       pbw = (unsigned*)pb;

    bf16x8 k0 = kf[0], k1 = kf[64];
    bf16x8 v0 = vf[0], v1 = vf[64];

    for (int c = 0; c < 64; ++c) {
        const int cn = (c + 1) & 63;   // wrap: re-load chunk 0 once, harmless
        bf16x8 nk0 = kf[(size_t)cn * 128];
        bf16x8 nk1 = kf[(size_t)cn * 128 + 64];
        bf16x8 nv0 = vf[(size_t)cn * 128];
        bf16x8 nv1 = vf[(size_t)cn * 128 + 64];

        // scores: tile0 = even keys (p=2*l16), tile1 = odd keys (p=2*l16+1)
        f32x4 s0 = __builtin_amdgcn_mfma_f32_16x16x32_bf16(aQ.v, k0, zero, 0, 0, 0);
        f32x4 s1 = __builtin_amdgcn_mfma_f32_16x16x32_bf16(aQ.v, k1, zero, 0, 0, 0);

        #pragma unroll
        for (int r = 0; r < 4; ++r) {
            float e0  = __builtin_amdgcn_exp2f(s0[r]);
            float en0 = __builtin_amdgcn_exp2f(-s0[r]);
            float e1  = __builtin_amdgcn_exp2f(s1[r]);
            float en1 = __builtin_amdgcn_exp2f(-s1[r]);
            den[r] += (e0 + en0) + (e1 + en1);
            // P[q=quad*4+r][cols 2*l16, 2*l16+1] packed -> one b32 write
            pbw[(quad * 4 + r) * (PROW / 2) + l16] = pk2(e0 - en0, e1 - en1);
        }

        // P: C-layout -> A-layout (lane holds P[q=l16][p = quad*8..+7])
        bf16x8 aP = *(const bf16x8*)(pb + l16 * PROW + quad * 8);

        o0 = __builtin_amdgcn_mfma_f32_16x16x32_bf16(aP, v0, o0, 0, 0, 0);
        o1 = __builtin_amdgcn_mfma_f32_16x16x32_bf16(aP, v1, o1, 0, 0, 0);

        k0 = nk0; k1 = nk1; v0 = nv0; v1 = nv1;
    }

    // den: sum across the 16 key-column lanes of each quad group
    #pragma unroll
    for (int r = 0; r < 4; ++r) {
        den[r] += __shfl_xor(den[r], 1, 16);
        den[r] += __shfl_xor(den[r], 2, 16);
        den[r] += __shfl_xor(den[r], 4, 16);
        den[r] += __shfl_xor(den[r], 8, 16);
    }

    float* outp = Out + ((size_t)bh * SLEN + qbase) * DK;
    #pragma unroll
    for (int r = 0; r < 4; ++r) {
        float inv = 1.0f / den[r];
        int q = quad * 4 + r;
        outp[(size_t)q * DK + l16]      = o0[r] * inv;
        outp[(size_t)q * DK + 16 + l16] = o1[r] * inv;
    }
}

extern "C" void kernel_launch(void* const* d_in, const int* in_sizes, int n_in,
                              void* d_out, int out_size, void* d_ws, size_t ws_size,
                              hipStream_t stream) {
    const float* Q = (const float*)d_in[0];
    const float* K = (const float*)d_in[1];
    const float* V = (const float*)d_in[2];
    // d_in[3] = attn_mask: no-op in reference, never read
    float* Out = (float*)d_out;
    unsigned short* Kbf = (unsigned short*)d_ws;                      // 6.29 MB
    unsigned short* VTf = Kbf + (size_t)NBH * SLEN * DK;              // 6.29 MB

    prep_k<<<dim3(NBH * 32), dim3(256), 0, stream>>>(K, Kbf);
    prep_v<<<dim3(NBH * 64), dim3(256), 0, stream>>>(V, VTf);
    attn_mfma<<<dim3(NBH * 32), dim3(256), 0, stream>>>(Q, Kbf, VTf, Out);
}

// Round 4
// 926.386 us; speedup vs baseline: 1.5704x; 1.0085x over previous
//
#include <hip/hip_runtime.h>
#include <hip/hip_bf16.h>
#include <cstdint>
#include <cstddef>

// tanh_max attention, B=4 H=12 S=2048 D=32, fp32 in/out. attn_mask is a
// faithful no-op in the reference -> never read.
//
// R4: latency attack on the R3 structure (which was chain-latency-bound:
// score->exp->pack->write->read->PV serialized per chunk, 6 waves/SIMD).
//   - software pipeline with DOUBLE-BUFFERED P in LDS: P(c) is written in
//     iteration c-1 and read in iteration c -> the LDS round-trip and the
//     K-frag loads each get a full iteration of load->use distance.
//   - 2-way key split: block = 2 q-tiles x 2 key-halves (4 waves); each
//     wave does 1024 keys; wave pairs combine num/den via LDS + 1 barrier.
//     Grid 3072 -> more resident waves/SIMD for latency hiding.
//   - preps fused into one kernel (one launch).

#define SLEN 2048
#define DK   32
#define NBH  48
#define PROW 40   // P-buffer row stride in bf16 (80 B, 16B-aligned)
#define NCH  32   // 32-key chunks per wave (half of 64)

typedef __attribute__((ext_vector_type(8))) short bf16x8;
typedef __attribute__((ext_vector_type(4))) float f32x4;

__device__ __forceinline__ unsigned pk2(float a, float b) {
    __hip_bfloat162 h = __float22bfloat162_rn(make_float2(a, b));
    union { __hip_bfloat162 h2; unsigned u; } cv; cv.h2 = h; return cv.u;
}

// ---- fused prep: K -> Kbf (frag order, even/odd interleave);
//                  V -> VTf (V^T frag order) --------------------------------
// Kbf frag ((bh*128 + t)*64 + l): t = 2c+tb, key = c*32 + 2*(l&15) + tb,
//   elems K[bh][key][(l>>4)*8 + j], j=0..7.
// VTf frag (((bh*64 + c)*2 + h)*64 + l): elems V[bh][c*32+(l>>4)*8+j][h*16+(l&15)].
__global__ __launch_bounds__(256)
void prep_kv(const float* __restrict__ K, const float* __restrict__ V,
             unsigned short* __restrict__ Kbf, unsigned short* __restrict__ VTf) {
    if (blockIdx.x < NBH * 32) {
        const int b  = blockIdx.x;
        const int bh = b >> 5, kg = b & 31;
        const int tl = threadIdx.x >> 6, l = threadIdx.x & 63;
        const int t  = kg * 4 + tl;
        const int c  = t >> 1, tb = t & 1;
        const int key = c * 32 + 2 * (l & 15) + tb;
        const float* src = K + ((size_t)bh * SLEN + key) * DK + (l >> 4) * 8;
        float4 a = *(const float4*)src;
        float4 b4 = *(const float4*)(src + 4);
        union { uint4 q; unsigned u[4]; } o;
        o.u[0] = pk2(a.x, a.y);  o.u[1] = pk2(a.z, a.w);
        o.u[2] = pk2(b4.x, b4.y); o.u[3] = pk2(b4.z, b4.w);
        *(uint4*)(Kbf + (((size_t)bh * 128 + t) * 64 + l) * 8) = o.q;
    } else {
        __shared__ float tile[32][33];
        const int b  = blockIdx.x - NBH * 32;
        const int bh = b >> 6, c = b & 63;
        const int t  = threadIdx.x;
        {
            const int row = t >> 3, c4 = (t & 7) * 4;
            float4 v4 = *(const float4*)(V + ((size_t)bh * SLEN + c * 32 + row) * DK + c4);
            tile[row][c4 + 0] = v4.x; tile[row][c4 + 1] = v4.y;
            tile[row][c4 + 2] = v4.z; tile[row][c4 + 3] = v4.w;
        }
        __syncthreads();
        const int h = t >> 7, l = (t >> 1) & 63, jh = t & 1;
        const int col = h * 16 + (l & 15);
        const int r0  = (l >> 4) * 8 + jh * 4;
        uint2 u;
        u.x = pk2(tile[r0 + 0][col], tile[r0 + 1][col]);
        u.y = pk2(tile[r0 + 2][col], tile[r0 + 3][col]);
        *(uint2*)(VTf + ((((size_t)bh * 64 + c) * 2 + h) * 64 + l) * 8 + jh * 4) = u;
    }
}

// ---- main: pipelined MFMA attention ----------------------------------------
__global__ __launch_bounds__(256, 6)
void attn_mfma(const float* __restrict__ Q, const unsigned short* __restrict__ Kbf,
               const unsigned short* __restrict__ VTf, float* __restrict__ Out) {
    __shared__ __align__(16) unsigned short Pbuf[4][2][16 * PROW];  // 10240 B
    __shared__ __align__(16) float Red[2][64][12];                  //  6144 B

    const int tid  = threadIdx.x;
    const int lane = tid & 63;
    const int wv   = tid >> 6;
    const int quad = lane >> 4;
    const int l16  = lane & 15;
    const int qi   = wv >> 1;          // which q-tile of the block's pair
    const int kh   = wv & 1;           // which key half (0: 0..1023, 1: 1024..2047)

    // XCD-aware head clustering: 6 heads per XCD.
    const int b   = blockIdx.x;        // grid = 3072
    const int xcd = b & 7;
    const int i   = b >> 3;            // 0..383
    const int bh  = xcd * 6 + (i % 6);
    const int qp  = i / 6;             // 0..63 q-tile pairs
    const int qbase = (qp * 2 + qi) * 16;

    // Q a-frag, scaled by (1/sqrt(32))*log2(e) -> log2-domain scores
    const float sc = 0.17677669529663687f * 1.4426950408889634f;
    const float* qp_ = Q + ((size_t)bh * SLEN + qbase + l16) * DK + quad * 8;
    float4 qa = *(const float4*)qp_;
    float4 qb = *(const float4*)(qp_ + 4);
    union { bf16x8 v; unsigned u[4]; } aQ;
    aQ.u[0] = pk2(qa.x * sc, qa.y * sc); aQ.u[1] = pk2(qa.z * sc, qa.w * sc);
    aQ.u[2] = pk2(qb.x * sc, qb.y * sc); aQ.u[3] = pk2(qb.z * sc, qb.w * sc);

    // frag streams for this wave's key half (chunk c: tiles at c*128 + {0,64})
    const bf16x8* kf = (const bf16x8*)Kbf + (size_t)bh * 8192 + (size_t)kh * 4096 + lane;
    const bf16x8* vf = (const bf16x8*)VTf + (size_t)bh * 8192 + (size_t)kh * 4096 + lane;

    f32x4 o0 = {0.f, 0.f, 0.f, 0.f};
    f32x4 o1 = {0.f, 0.f, 0.f, 0.f};
    f32x4 den = {0.f, 0.f, 0.f, 0.f};
    const f32x4 zero = {0.f, 0.f, 0.f, 0.f};

    unsigned short* pb  = &Pbuf[wv][0][0];
    unsigned*       pbw = (unsigned*)pb;

    auto exppack = [&](const f32x4& s0, const f32x4& s1, int buf) {
        unsigned* pw = pbw + buf * (16 * PROW / 2);
        #pragma unroll
        for (int r = 0; r < 4; ++r) {
            float e0  = __builtin_amdgcn_exp2f(s0[r]);
            float en0 = __builtin_amdgcn_exp2f(-s0[r]);
            float e1  = __builtin_amdgcn_exp2f(s1[r]);
            float en1 = __builtin_amdgcn_exp2f(-s1[r]);
            den[r] += (e0 + en0) + (e1 + en1);
            pw[(quad * 4 + r) * (PROW / 2) + l16] = pk2(e0 - en0, e1 - en1);
        }
    };
    auto readP = [&](int buf) -> bf16x8 {
        return *(const bf16x8*)(pb + buf * (16 * PROW) + l16 * PROW + quad * 8);
    };

    // ---- prologue: chunk 0 scores + P(0); preload k(1) ----
    bf16x8 ka = kf[0], kb = kf[64];
    bf16x8 v_cur0 = vf[0], v_cur1 = vf[64];
    f32x4 s0 = __builtin_amdgcn_mfma_f32_16x16x32_bf16(aQ.v, ka, zero, 0, 0, 0);
    f32x4 s1 = __builtin_amdgcn_mfma_f32_16x16x32_bf16(aQ.v, kb, zero, 0, 0, 0);
    ka = kf[128]; kb = kf[192];
    exppack(s0, s1, 0);

    // ---- steady state ----
    for (int c = 0; c < NCH - 1; ++c) {
        // scores(c+1) with K-frags loaded one iteration ago
        s0 = __builtin_amdgcn_mfma_f32_16x16x32_bf16(aQ.v, ka, zero, 0, 0, 0);
        s1 = __builtin_amdgcn_mfma_f32_16x16x32_bf16(aQ.v, kb, zero, 0, 0, 0);
        // prefetch k(c+2) (wrapped: tail re-loads chunk 0/1, harmless)
        const int c2 = (c + 2) & (NCH - 1);
        ka = kf[(size_t)c2 * 128]; kb = kf[(size_t)c2 * 128 + 64];
        // v(c+1)
        bf16x8 v_nxt0 = vf[(size_t)(c + 1) * 128];
        bf16x8 v_nxt1 = vf[(size_t)(c + 1) * 128 + 64];
        // read P(c) -- written last iteration, round-trip already complete
        bf16x8 aP = readP(c & 1);
        // exp/pack/write P(c+1) into the other buffer
        exppack(s0, s1, (c + 1) & 1);
        // PV(c)
        o0 = __builtin_amdgcn_mfma_f32_16x16x32_bf16(aP, v_cur0, o0, 0, 0, 0);
        o1 = __builtin_amdgcn_mfma_f32_16x16x32_bf16(aP, v_cur1, o1, 0, 0, 0);
        v_cur0 = v_nxt0; v_cur1 = v_nxt1;
    }
    // ---- epilogue: PV(last) ----
    {
        bf16x8 aP = readP((NCH - 1) & 1);
        o0 = __builtin_amdgcn_mfma_f32_16x16x32_bf16(aP, v_cur0, o0, 0, 0, 0);
        o1 = __builtin_amdgcn_mfma_f32_16x16x32_bf16(aP, v_cur1, o1, 0, 0, 0);
    }

    // den: reduce across the 16 key-column lanes of each quad group
    #pragma unroll
    for (int r = 0; r < 4; ++r) {
        den[r] += __shfl_xor(den[r], 1, 16);
        den[r] += __shfl_xor(den[r], 2, 16);
        den[r] += __shfl_xor(den[r], 4, 16);
        den[r] += __shfl_xor(den[r], 8, 16);
    }

    // cross-wave (key-half) combine
    if (kh == 1) {
        float* r = &Red[qi][lane][0];
        *(f32x4*)(r + 0) = o0;
        *(f32x4*)(r + 4) = o1;
        *(f32x4*)(r + 8) = den;
    }
    __syncthreads();
    if (kh == 0) {
        const float* r = &Red[qi][lane][0];
        f32x4 p0 = *(const f32x4*)(r + 0);
        f32x4 p1 = *(const f32x4*)(r + 4);
        f32x4 pd = *(const f32x4*)(r + 8);
        o0 += p0; o1 += p1; den += pd;

        float* outp = Out + ((size_t)bh * SLEN + qbase) * DK;
        #pragma unroll
        for (int rr = 0; rr < 4; ++rr) {
            float inv = 1.0f / den[rr];
            int q = quad * 4 + rr;
            outp[(size_t)q * DK + l16]      = o0[rr] * inv;
            outp[(size_t)q * DK + 16 + l16] = o1[rr] * inv;
        }
    }
}

extern "C" void kernel_launch(void* const* d_in, const int* in_sizes, int n_in,
                              void* d_out, int out_size, void* d_ws, size_t ws_size,
                              hipStream_t stream) {
    const float* Q = (const float*)d_in[0];
    const float* K = (const float*)d_in[1];
    const float* V = (const float*)d_in[2];
    // d_in[3] = attn_mask: no-op in reference, never read
    float* Out = (float*)d_out;
    unsigned short* Kbf = (unsigned short*)d_ws;                      // 6.29 MB
    unsigned short* VTf = Kbf + (size_t)NBH * SLEN * DK;              // 6.29 MB

    prep_kv<<<dim3(NBH * 32 + NBH * 64), dim3(256), 0, stream>>>(K, V, Kbf, VTf);
    attn_mfma<<<dim3(3072), dim3(256), 0, stream>>>(Q, Kbf, VTf, Out);
}